// Round 14
// baseline (155.384 us; speedup 1.0000x reference)
//
#include <hip/hip_runtime.h>
#include <stdint.h>

typedef unsigned short u16;
typedef unsigned int u32;
typedef unsigned int u32x2 __attribute__((ext_vector_type(2)));
typedef float f32x4 __attribute__((ext_vector_type(4)));
typedef __bf16 bf16x8 __attribute__((ext_vector_type(8)));

#define BS 2
#define SEQ 2048
#define DIM 1024
#define NW3 3072
#define NH 16
#define HD 64

#define MFMA_BF16(a, b, c) __builtin_amdgcn_mfma_f32_16x16x32_bf16((a), (b), (c), 0, 0, 0)

// async global->LDS, 16B per lane; LDS dest must be wave-uniform base + lane*16
#define GLL16(g, l)                                                                \
  __builtin_amdgcn_global_load_lds(                                                \
      (__attribute__((address_space(1))) void*)(void*)(uintptr_t)(g),              \
      (__attribute__((address_space(3))) void*)(l), 16, 0, 0)

__device__ __forceinline__ float fexp2(float x) {
#if defined(__has_builtin)
#if __has_builtin(__builtin_amdgcn_exp2f)
  return __builtin_amdgcn_exp2f(x);
#else
  return exp2f(x);
#endif
#else
  return exp2f(x);
#endif
}

__device__ __forceinline__ u16 f2bf(float x) {
  __bf16 h = (__bf16)x;
  return __builtin_bit_cast(u16, h);
}

#define CSC 0.18033688011112042f  // 0.125 * log2(e), folded into Q at gemm epilogue

#if defined(__has_builtin)
#if __has_builtin(__builtin_amdgcn_permlane32_swap) && \
    __has_builtin(__builtin_amdgcn_permlane16_swap)
#define HAVE_PLSWAP 1
#endif
#endif

// P-transform: redistribute packed P words for the PV B-fragment.
// permlane path (gfx950, pure VALU, 4 ops, R4-verified: BANK_CONFLICT 4.19M->0,
// attn 66.5->53.7us): pl32swap pair + pl16swap pair; both outputs usable.
__device__ __forceinline__ uint4 p_transform(u32 pk00, u32 pk01, u32 pk10, u32 pk11,
                                             int sl0, int sl1, bool hi) {
#ifdef HAVE_PLSWAP
  u32x2 s0 = __builtin_amdgcn_permlane32_swap(pk00, pk10, false, false);
  u32x2 s1 = __builtin_amdgcn_permlane32_swap(pk01, pk11, false, false);
  u32x2 t0 = __builtin_amdgcn_permlane16_swap(s0[0], s0[1], false, false);
  u32x2 t1 = __builtin_amdgcn_permlane16_swap(s1[0], s1[1], false, false);
  uint4 wv;
  wv.x = t0[0]; wv.y = t1[0]; wv.z = t0[1]; wv.w = t1[1];
  return wv;
#else
  u32 a0 = __shfl(pk00, sl0), a1 = __shfl(pk01, sl0);
  u32 a2 = __shfl(pk00, sl1), a3 = __shfl(pk01, sl1);
  u32 b0 = __shfl(pk10, sl0), b1 = __shfl(pk11, sl0);
  u32 b2 = __shfl(pk10, sl1), b3 = __shfl(pk11, sl1);
  uint4 wv;
  wv.x = hi ? b0 : a0; wv.y = hi ? b1 : a1;
  wv.z = hi ? b2 : a2; wv.w = hi ? b3 : a3;
  return wv;
#endif
}

// ---------------- fused fp32->bf16 converts (R5 LDS tile-transpose W-part) ------
__global__ __launch_bounds__(256) void conv_kernel(const float* __restrict__ A,
                                                   u16* __restrict__ O,
                                                   const float* __restrict__ W,
                                                   u16* __restrict__ Wt) {
  if (blockIdx.x < 4096) {
    int i = (blockIdx.x * 256 + threadIdx.x) * 4;
    float4 v = *(const float4*)(A + i);
    union { u16 u[4]; ushort4 v4; } p;
    p.u[0] = f2bf(v.x); p.u[1] = f2bf(v.y); p.u[2] = f2bf(v.z); p.u[3] = f2bf(v.w);
    *(ushort4*)(O + i) = p.v4;
  } else {
    __shared__ __align__(16) u16 lt[64][68];  // 8.7 KB, stride 136 B
    int b2 = blockIdx.x - 4096;               // 0..767 = 16 k-tiles x 48 n-tiles
    int ktile = b2 / 48, ntile = b2 - ktile * 48;
    int k0 = ktile * 64, n0 = ntile * 64;
    int rowb = threadIdx.x >> 4, c4 = (threadIdx.x & 15) * 4;
#pragma unroll
    for (int rr = 0; rr < 4; ++rr) {
      int row = rowb + rr * 16;  // k within tile
      float4 v = *(const float4*)(W + (size_t)(k0 + row) * NW3 + n0 + c4);
      union { u16 u[4]; uint2 d; } pk;
      pk.u[0] = f2bf(v.x); pk.u[1] = f2bf(v.y); pk.u[2] = f2bf(v.z); pk.u[3] = f2bf(v.w);
      *(uint2*)&lt[row][c4] = pk.d;
    }
    __syncthreads();
    int j = threadIdx.x >> 2, seg = threadIdx.x & 3;  // j = n within tile
    int n = n0 + j;
    int h = n & 15, hd = (n & 1023) >> 4;
    int np = (n & ~1023) + h * 64 + hd;               // permuted row (head-grouped)
    union { u16 u[16]; uint4 q[2]; } o;
#pragma unroll
    for (int idx = 0; idx < 16; ++idx) o.u[idx] = lt[seg * 16 + idx][j];  // column read
    u16* dst = Wt + (size_t)np * DIM + k0 + seg * 16;
    *(uint4*)(dst) = o.q[0];
    *(uint4*)(dst + 8) = o.q[1];
  }
}

// ---------------- QKV GEMM v6: triple-buffer counted-vmcnt (R12, kept) ----------
#define GSTAGE(ADST, BDST, KT)                                                 \
  {                                                                            \
    const int koff = (KT) * 64; /* 32 k * 2 B */                               \
    _Pragma("unroll") for (int r = 0; r < 2; ++r) {                            \
      int l = r * 256 + t;        /* 16B chunk id 0..511 */                    \
      int row = l >> 2, pos = l & 3;                                           \
      int kc = pos ^ (row & 3);                                                \
      GLL16(Abase + row * 2048 + koff + kc * 16, (char*)(ADST) + l * 16);      \
      GLL16(Bbase + row * 2048 + koff + kc * 16, (char*)(BDST) + l * 16);      \
    }                                                                          \
  }

#define GCOMPUTE(AT, BT)                                                       \
  {                                                                            \
    bf16x8 af[4], bfr[4];                                                      \
    _Pragma("unroll") for (int mt = 0; mt < 4; ++mt) {                         \
      int row = wm + mt * 16 + c;                                              \
      int kc = quad ^ (row & 3);                                               \
      af[mt] = *(const bf16x8*)((const char*)(AT) + row * 64 + kc * 16);       \
    }                                                                          \
    _Pragma("unroll") for (int nt = 0; nt < 4; ++nt) {                         \
      int row = wn + nt * 16 + c;                                              \
      int kc = quad ^ (row & 3);                                               \
      bfr[nt] = *(const bf16x8*)((const char*)(BT) + row * 64 + kc * 16);      \
    }                                                                          \
    _Pragma("unroll") for (int mt = 0; mt < 4; ++mt)                           \
      _Pragma("unroll") for (int nt = 0; nt < 4; ++nt)                         \
        acc[mt][nt] = MFMA_BF16(af[mt], bfr[nt], acc[mt][nt]);                 \
  }

__global__ __launch_bounds__(256) void gemm_qkv_kernel(
    const u16* __restrict__ Ab, const u16* __restrict__ Bt, const float* __restrict__ bias,
    u16* __restrict__ Q, u16* __restrict__ K, u16* __restrict__ Vt) {
  __shared__ __align__(16) u16 A0[128 * 32];  // 8 KB x6 = 48 KB (3 blk/CU, = grid cap)
  __shared__ __align__(16) u16 A1[128 * 32];
  __shared__ __align__(16) u16 A2[128 * 32];
  __shared__ __align__(16) u16 B0[128 * 32];
  __shared__ __align__(16) u16 B1[128 * 32];
  __shared__ __align__(16) u16 B2[128 * 32];
  const int t = threadIdx.x;
  const int lane = t & 63, wave = t >> 6;
  const int c = lane & 15, quad = lane >> 4;
  // XCD swizzle: 96 consecutive block ids per XCD (768 = 8*96, bijective)
  const int wid = (blockIdx.x & 7) * 96 + (blockIdx.x >> 3);
  const int tm = wid / 24, tn = wid - tm * 24;
  const int wm = (wave >> 1) * 64, wn = (wave & 1) * 64;

  const char* Abase = (const char*)(Ab + (size_t)tm * 128 * DIM);
  const char* Bbase = (const char*)(Bt + (size_t)tn * 128 * DIM);

  f32x4 z = {0.f, 0.f, 0.f, 0.f};
  f32x4 acc[4][4];
#pragma unroll
  for (int i = 0; i < 4; ++i)
#pragma unroll
    for (int j = 0; j < 4; ++j) acc[i][j] = z;

  // prologue: stages 0,1 in flight; wait only stage 0 (4 loads of stage 1 remain)
  GSTAGE(A0, B0, 0);
  GSTAGE(A1, B1, 1);
  asm volatile("s_waitcnt vmcnt(4)" ::: "memory");
  __builtin_amdgcn_s_barrier();
  __builtin_amdgcn_sched_barrier(0);

  const u16 *pa = A0, *pb = B0;   // compute buffer (tile kt)
  const u16 *qa = A1, *qb = B1;   // next (tile kt+1)
  const u16 *ra = A2, *rb = B2;   // staging target (tile kt+2)
#pragma unroll 1
  for (int kt = 0; kt < 32; ++kt) {
    if (kt + 2 < 32) GSTAGE(ra, rb, kt + 2);  // 2 stages in flight
    GCOMPUTE(pa, pb);
    if (kt + 2 < 32) {
      asm volatile("s_waitcnt vmcnt(4)" ::: "memory");  // stage kt+1 landed
    } else {
      asm volatile("s_waitcnt vmcnt(0)" ::: "memory");  // tail drain
    }
    __builtin_amdgcn_s_barrier();   // raw: stage kt+2 stays in flight across it
    __builtin_amdgcn_sched_barrier(0);
    const u16* ta = pa; pa = qa; qa = ra; ra = ta;
    const u16* tb = pb; pb = qb; qb = rb; rb = tb;
  }

  // Epilogue (R8-proven): C/D layout col = lane&15, row = quad*4 + reg.
#pragma unroll
  for (int nt = 0; nt < 4; ++nt) {
    int np = tn * 128 + wn + nt * 16 + c;
    int which = np >> 10;
    int rem = np & 1023;
    int h = rem >> 6, hd = rem & 63;
    float bv = bias[(np & ~1023) + hd * 16 + h];  // bias in ORIGINAL column order
    float sc = (which == 0) ? CSC : 1.0f;
    float bvs = bv * sc;
#pragma unroll
    for (int mt = 0; mt < 4; ++mt) {
      int mbase = tm * 128 + wm + mt * 16 + quad * 4;
      int bI = mbase >> 11;
      int s0 = mbase & 2047;
      if (which == 2) {
        union { u16 u[4]; uint2 v; } p;
#pragma unroll
        for (int r = 0; r < 4; ++r) p.u[r] = f2bf(acc[mt][nt][r] + bv);
        *(uint2*)(Vt + ((size_t)(bI * NH + h) * HD + hd) * SEQ + s0) = p.v;  // [b,h,hd,s]
      } else {
        u16* dst = (which == 0) ? Q : K;
#pragma unroll
        for (int r = 0; r < 4; ++r)
          dst[((size_t)(bI * NH + h) * SEQ + (s0 + r)) * HD + hd] =
              f2bf(acc[mt][nt][r] * sc + bvs);
      }
    }
  }
}

// ---------------- Flash attention v18: v17 qt-paired + counted-vmcnt pipeline ---
// R13: v17 (qt-paired 8-wave) = best total 155.3; attn ~50.4, still no pipe
// saturated (MfmaUtil 31, VALU 48). v18 removes the last known structural
// stall: each __syncthreads drained (vmcnt 0 + lgkm 0) the just-issued stage,
// 32x/block. Port of the v11 triple-buffer counted-vmcnt loop (correctness-
// validated in R2, incl. the R1 lgkmcnt(0) Q-race fix) into v17's structure.
// Unlike R2's attempt, the 3rd K/V buffer is FREE here: grid 512 = 2 blk/CU
// (grid-capped) and 50KB LDS still admits 3 -- occupancy unchanged.
// vmcnt audit (per thread, 2 GLL per STAGE_KV / Q-stage): prologue
// Q(2)+s0(2)+s1(2)=6 -> vmcnt(4) Q landed -> qf ds_reads -> vmcnt(2)+lgkm(0)
// (s0 landed; Q reads drained before K0/V0 reuse) -> steady: stage kt+2
// (in-flight 4) -> compute kt -> vmcnt(2) (kt+1 landed; kt+2 in flight across
// raw barrier) -> tail vmcnt(0). MFMAs consume all ds_reads before each
// barrier (compiler lgkm waits); sched_barrier(0) seals each iter (rule #18).
#define STAGE_KV(KDST, VDST, KTILE)                                            \
  {                                                                            \
    const char* Ktb = Kb + (size_t)(KTILE) * 8192;   /* 64 rows * 128 B */     \
    const char* Vtb = Vb + (size_t)(KTILE) * 128;    /* 64 cols * 2 B   */     \
    int l = t;                      /* 512 threads = 512 x 16B chunks */       \
    int row = l >> 3, pos = l & 7;                                             \
    int kc = pos ^ (row & 7);                                                  \
    GLL16(Ktb + row * 128 + kc * 16, (char*)(KDST) + l * 16);                  \
    GLL16(Vtb + row * 4096 + kc * 16, (char*)(VDST) + l * 16);                 \
  }

#define COMPUTE_TILE(KT, VT)                                                   \
  {                                                                            \
    f32x4 sT[2][2]; /* [mt2 = s_k 16-tile within wave's half][nt = s_q tile] */\
    sT[0][0] = z; sT[0][1] = z; sT[1][0] = z; sT[1][1] = z;                    \
    __builtin_amdgcn_s_setprio(1);                                             \
    _Pragma("unroll") for (int mt2 = 0; mt2 < 2; ++mt2) {                      \
      _Pragma("unroll") for (int ks = 0; ks < 2; ++ks) {                       \
        int row = ws * 32 + mt2 * 16 + c;                                      \
        int kc = (ks * 4 + quad) ^ (row & 7);                                  \
        bf16x8 kf = *(const bf16x8*)((const char*)(KT) + row * 128 + kc * 16); \
        sT[mt2][0] = MFMA_BF16(kf, qf[0][ks], sT[mt2][0]);                     \
        sT[mt2][1] = MFMA_BF16(kf, qf[1][ks], sT[mt2][1]);                     \
      }                                                                        \
    }                                                                          \
    __builtin_amdgcn_s_setprio(0);                                             \
    bf16x8 pf[2];                                                              \
    _Pragma("unroll") for (int nt = 0; nt < 2; ++nt) {                         \
      u32 pk[2][2];                                                            \
      _Pragma("unroll") for (int mt2 = 0; mt2 < 2; ++mt2) {                    \
        float p0 = fexp2(sT[mt2][nt][0]);                                      \
        float p1 = fexp2(sT[mt2][nt][1]);                                      \
        float p2 = fexp2(sT[mt2][nt][2]);                                      \
        float p3 = fexp2(sT[mt2][nt][3]);                                      \
        pk[mt2][0] = (u32)f2bf(p0) | ((u32)f2bf(p1) << 16);                    \
        pk[mt2][1] = (u32)f2bf(p2) | ((u32)f2bf(p3) << 16);                    \
      }                                                                        \
      uint4 wv = p_transform(pk[0][0], pk[0][1], pk[1][0], pk[1][1],           \
                             sl0, sl1, hi);                                    \
      pf[nt] = __builtin_bit_cast(bf16x8, wv);                                 \
    }                                                                          \
    __builtin_amdgcn_s_setprio(1);                                             \
    _Pragma("unroll") for (int mt = 0; mt < 4; ++mt) {                         \
      int row = mt * 16 + c;                                                   \
      int kc = vq ^ (row & 7);                                                 \
      bf16x8 vf = *(const bf16x8*)((const char*)(VT) + row * 128 + kc * 16);   \
      accO[mt][0] = MFMA_BF16(vf, pf[0], accO[mt][0]);                         \
      accO[mt][1] = MFMA_BF16(vf, pf[1], accO[mt][1]);                         \
    }                                                                          \
    acc_l[0] = MFMA_BF16(ones, pf[0], acc_l[0]);  /* col-sums of P = l partial */ \
    acc_l[1] = MFMA_BF16(ones, pf[1], acc_l[1]);                               \
    __builtin_amdgcn_s_setprio(0);                                             \
  }

__global__ __launch_bounds__(512, 4) void attn_kernel(
    const u16* __restrict__ Q, const u16* __restrict__ K,
    const u16* __restrict__ Vt, float* __restrict__ Out) {
  __shared__ __align__(16) u16 K0[64 * 64];   // 8 KB (Q tile0 staging / reduce wq2=0)
  __shared__ __align__(16) u16 K1[64 * 64];   // 8 KB (reduce wq2=1)
  __shared__ __align__(16) u16 K2[64 * 64];   // 8 KB (reduce wq2=2)
  __shared__ __align__(16) u16 V0[64 * 64];   // 8 KB (Q tile1 staging / reduce wq2=3)
  __shared__ __align__(16) u16 V1[64 * 64];   // 8 KB
  __shared__ __align__(16) u16 V2[64 * 64];   // 8 KB   -> 48 KB + lred
  __shared__ float lred[512];                 // 2 KB  l partials (4 wq2 x 128)
  const int t = threadIdx.x;
  const int lane = t & 63, wave = t >> 6;     // 8 waves
  const int c = lane & 15, quad = lane >> 4;
  const int wq2 = wave & 3, ws = wave >> 2;   // q 32-row group (of 128) / s_k half
  // XCD-aware swizzle: p%8 selects XCD; each XCD gets 4 whole bh's (2MB K/V in L2)
  const int p = blockIdx.x;                   // 512 blocks = 32 bh x 16 qt-pairs
  const int xcd = p & 7, slot = p >> 3;       // slot 0..63
  const int bh = xcd + ((slot >> 4) << 3);    // bh ≡ xcd (mod 8), 4 bh per XCD
  const int qtp = slot & 15;                  // q-tile-pair: rows qtp*128 .. +128
  const int h = bh & 15, b = bh >> 4;

  const u16* Qb = Q + ((size_t)bh * SEQ + qtp * 128) * HD;
  const char* Kb = (const char*)(K + (size_t)bh * SEQ * HD);
  const char* Vb = (const char*)(Vt + (size_t)bh * HD * SEQ);

  // ---- prologue: Q pair (tile0->K0, tile1->V0) + KV stages 0,1; counted waits --
  {
    int l = t;
    int row = l >> 3, pos = l & 7;
    int kc = pos ^ (row & 7);
    GLL16((const char*)Qb + row * 128 + kc * 16, (char*)K0 + l * 16);
    GLL16((const char*)Qb + 8192 + row * 128 + kc * 16, (char*)V0 + l * 16);
  }
  STAGE_KV(K1, V1, 0);
  STAGE_KV(K2, V2, 1);
  asm volatile("s_waitcnt vmcnt(4)" ::: "memory");  // Q's 2 loads landed
  __builtin_amdgcn_s_barrier();
  __builtin_amdgcn_sched_barrier(0);
  bf16x8 qf[2][2];  // [nt][ks]; wave's q rows = qtp*128 + wq2*32 + nt*16 + c
#pragma unroll
  for (int nt = 0; nt < 2; ++nt)
#pragma unroll
    for (int ks = 0; ks < 2; ++ks) {
      int row = (wq2 & 1) * 32 + nt * 16 + c;   // row within the 64-row tile
      int kc = (ks * 4 + quad) ^ (row & 7);
      const char* qbuf = (wq2 >> 1) ? (const char*)V0 : (const char*)K0;
      qf[nt][ks] = *(const bf16x8*)(qbuf + row * 128 + kc * 16);
    }
  // lgkmcnt(0) REQUIRED: qf ds_reads must be processed before any wave passes
  // this barrier and re-stages K0/V0 (kt=0). vmcnt(2) = stage 0 landed.
  asm volatile("s_waitcnt vmcnt(2) lgkmcnt(0)" ::: "memory");
  __builtin_amdgcn_s_barrier();
  __builtin_amdgcn_sched_barrier(0);

  f32x4 z = {0.f, 0.f, 0.f, 0.f};
  f32x4 accO[4][2];  // [mt = hd tile][nt]; partial over wave's s_k half
#pragma unroll
  for (int i = 0; i < 4; ++i) { accO[i][0] = z; accO[i][1] = z; }
  f32x4 acc_l[2] = {z, z};  // l partials via ones-MFMA (rows identical)
  const uint4 onesw = {0x3F803F80u, 0x3F803F80u, 0x3F803F80u, 0x3F803F80u};
  const bf16x8 ones = __builtin_bit_cast(bf16x8, onesw);

  const int sl0 = c + 16 * ((quad & 1) * 2);  // shuffle source lanes (fallback path)
  const int sl1 = sl0 + 16;
  const bool hi = quad >= 2;
  const int vq = ws * 4 + quad;  // V^T chunk index: s_k = ws*32 + quad*8 + j

  // rotating buffers: compute (tile kt), next (kt+1), stage target (kt+2)
  const u16 *pk_ = K1, *pv_ = V1;
  const u16 *nk_ = K2, *nv_ = V2;
  const u16 *sk_ = K0, *sv_ = V0;
#pragma unroll 1
  for (int kt = 0; kt < 32; ++kt) {
    if (kt + 2 < 32) STAGE_KV(sk_, sv_, kt + 2);  // 2 stages in flight
    COMPUTE_TILE(pk_, pv_);
    if (kt + 2 < 32) {
      asm volatile("s_waitcnt vmcnt(2)" ::: "memory");  // stage kt+1 landed
    } else {
      asm volatile("s_waitcnt vmcnt(0)" ::: "memory");  // tail drain
    }
    __builtin_amdgcn_s_barrier();   // raw: stage kt+2 stays in flight across it
    __builtin_amdgcn_sched_barrier(0);
    const u16* tk = pk_; pk_ = nk_; nk_ = sk_; sk_ = tk;
    const u16* tv = pv_; pv_ = nv_; nv_ = sv_; sv_ = tv;
  }

  // ---- cross-wave reduce over ws pairs (LDS buffers are free now) ----
  // acc_l rows identical (ones-MFMA): [0] = this wave's 32-k partial l for
  // q-col c, replicated across quads. Pair (ws=0,wq2) <-> (ws=1,wq2).
  float sm[2];
  sm[0] = acc_l[0][0];
  sm[1] = acc_l[1][0];
  float* fb = (float*)((wq2 & 2) ? ((wq2 & 1) ? (void*)V0 : (void*)K2)
                                 : ((wq2 & 1) ? (void*)K1 : (void*)K0));
  if (ws == 1) {
#pragma unroll
    for (int mt = 0; mt < 4; ++mt)
#pragma unroll
      for (int nt = 0; nt < 2; ++nt)
        *(f32x4*)(fb + (mt * 2 + nt) * 256 + lane * 4) = accO[mt][nt];
    lred[wq2 * 128 + lane * 2] = sm[0];
    lred[wq2 * 128 + lane * 2 + 1] = sm[1];
  }
  __syncthreads();
  if (ws == 0) {
#pragma unroll
    for (int mt = 0; mt < 4; ++mt)
#pragma unroll
      for (int nt = 0; nt < 2; ++nt)
        accO[mt][nt] += *(const f32x4*)(fb + (mt * 2 + nt) * 256 + lane * 4);
    float inv0 = 1.f / (sm[0] + lred[wq2 * 128 + lane * 2]);
    float inv1 = 1.f / (sm[1] + lred[wq2 * 128 + lane * 2 + 1]);
    int s0 = qtp * 128 + wq2 * 32 + c;
#pragma unroll
    for (int mt = 0; mt < 4; ++mt) {
#pragma unroll
      for (int nt = 0; nt < 2; ++nt) {
        float inv = nt ? inv1 : inv0;
        float4 o;
        o.x = accO[mt][nt][0] * inv;
        o.y = accO[mt][nt][1] * inv;
        o.z = accO[mt][nt][2] * inv;
        o.w = accO[mt][nt][3] * inv;
        size_t off = ((size_t)(b * SEQ + s0 + nt * 16)) * DIM + h * HD + mt * 16 + quad * 4;
        *(float4*)(Out + off) = o;
      }
    }
  }
}

extern "C" void kernel_launch(void* const* d_in, const int* in_sizes, int n_in,
                              void* d_out, int out_size, void* d_ws, size_t ws_size,
                              hipStream_t stream) {
  (void)in_sizes; (void)n_in; (void)out_size; (void)ws_size;
  const float* emb = (const float*)d_in[0];
  const float* W = (const float*)d_in[1];
  const float* bias = (const float*)d_in[2];
  float* out = (float*)d_out;
  char* ws = (char*)d_ws;
  // ws layout (bytes): Abf 8 MB | Wt 6 MB | Q 8 MB | K 8 MB | Vt 8 MB  (total ~38 MB)
  u16* Ab = (u16*)ws;
  u16* Wt = (u16*)(ws + 8388608);
  u16* Qd = (u16*)(ws + 14680064);
  u16* Kd = (u16*)(ws + 23068672);
  u16* Vd = (u16*)(ws + 31457280);

  conv_kernel<<<4864, 256, 0, stream>>>(emb, Ab, W, Wt);   // 4096 A-blocks + 768 W-tiles
  gemm_qkv_kernel<<<768, 256, 0, stream>>>(Ab, Wt, bias, Qd, Kd, Vd);
  attn_kernel<<<512, 512, 0, stream>>>(Qd, Kd, Vd, out);   // (b,h) x 16 q-tile-pairs of 128
}

// Round 15
// 153.747 us; speedup vs baseline: 1.0106x; 1.0106x over previous
//
#include <hip/hip_runtime.h>
#include <stdint.h>

typedef unsigned short u16;
typedef unsigned int u32;
typedef unsigned int u32x2 __attribute__((ext_vector_type(2)));
typedef float f32x4 __attribute__((ext_vector_type(4)));
typedef __bf16 bf16x8 __attribute__((ext_vector_type(8)));

#define BS 2
#define SEQ 2048
#define DIM 1024
#define NW3 3072
#define NH 16
#define HD 64

#define MFMA_BF16(a, b, c) __builtin_amdgcn_mfma_f32_16x16x32_bf16((a), (b), (c), 0, 0, 0)

// async global->LDS, 16B per lane; LDS dest must be wave-uniform base + lane*16
#define GLL16(g, l)                                                                \
  __builtin_amdgcn_global_load_lds(                                                \
      (__attribute__((address_space(1))) void*)(void*)(uintptr_t)(g),              \
      (__attribute__((address_space(3))) void*)(l), 16, 0, 0)

__device__ __forceinline__ float fexp2(float x) {
#if defined(__has_builtin)
#if __has_builtin(__builtin_amdgcn_exp2f)
  return __builtin_amdgcn_exp2f(x);
#else
  return exp2f(x);
#endif
#else
  return exp2f(x);
#endif
}

__device__ __forceinline__ u16 f2bf(float x) {
  __bf16 h = (__bf16)x;
  return __builtin_bit_cast(u16, h);
}

#define CSC 0.18033688011112042f  // 0.125 * log2(e), folded into Q at gemm epilogue

#if defined(__has_builtin)
#if __has_builtin(__builtin_amdgcn_permlane32_swap) && \
    __has_builtin(__builtin_amdgcn_permlane16_swap)
#define HAVE_PLSWAP 1
#endif
#endif

// P-transform: redistribute packed P words for the PV B-fragment.
// permlane path (gfx950, pure VALU, 4 ops, R4-verified: BANK_CONFLICT 4.19M->0,
// attn 66.5->53.7us): pl32swap pair + pl16swap pair; both outputs usable.
__device__ __forceinline__ uint4 p_transform(u32 pk00, u32 pk01, u32 pk10, u32 pk11,
                                             int sl0, int sl1, bool hi) {
#ifdef HAVE_PLSWAP
  u32x2 s0 = __builtin_amdgcn_permlane32_swap(pk00, pk10, false, false);
  u32x2 s1 = __builtin_amdgcn_permlane32_swap(pk01, pk11, false, false);
  u32x2 t0 = __builtin_amdgcn_permlane16_swap(s0[0], s0[1], false, false);
  u32x2 t1 = __builtin_amdgcn_permlane16_swap(s1[0], s1[1], false, false);
  uint4 wv;
  wv.x = t0[0]; wv.y = t1[0]; wv.z = t0[1]; wv.w = t1[1];
  return wv;
#else
  u32 a0 = __shfl(pk00, sl0), a1 = __shfl(pk01, sl0);
  u32 a2 = __shfl(pk00, sl1), a3 = __shfl(pk01, sl1);
  u32 b0 = __shfl(pk10, sl0), b1 = __shfl(pk11, sl0);
  u32 b2 = __shfl(pk10, sl1), b3 = __shfl(pk11, sl1);
  uint4 wv;
  wv.x = hi ? b0 : a0; wv.y = hi ? b1 : a1;
  wv.z = hi ? b2 : a2; wv.w = hi ? b3 : a3;
  return wv;
#endif
}

// ---------------- fused fp32->bf16 converts (R5 LDS tile-transpose W-part) ------
__global__ __launch_bounds__(256) void conv_kernel(const float* __restrict__ A,
                                                   u16* __restrict__ O,
                                                   const float* __restrict__ W,
                                                   u16* __restrict__ Wt) {
  if (blockIdx.x < 4096) {
    int i = (blockIdx.x * 256 + threadIdx.x) * 4;
    float4 v = *(const float4*)(A + i);
    union { u16 u[4]; ushort4 v4; } p;
    p.u[0] = f2bf(v.x); p.u[1] = f2bf(v.y); p.u[2] = f2bf(v.z); p.u[3] = f2bf(v.w);
    *(ushort4*)(O + i) = p.v4;
  } else {
    __shared__ __align__(16) u16 lt[64][68];  // 8.7 KB, stride 136 B
    int b2 = blockIdx.x - 4096;               // 0..767 = 16 k-tiles x 48 n-tiles
    int ktile = b2 / 48, ntile = b2 - ktile * 48;
    int k0 = ktile * 64, n0 = ntile * 64;
    int rowb = threadIdx.x >> 4, c4 = (threadIdx.x & 15) * 4;
#pragma unroll
    for (int rr = 0; rr < 4; ++rr) {
      int row = rowb + rr * 16;  // k within tile
      float4 v = *(const float4*)(W + (size_t)(k0 + row) * NW3 + n0 + c4);
      union { u16 u[4]; uint2 d; } pk;
      pk.u[0] = f2bf(v.x); pk.u[1] = f2bf(v.y); pk.u[2] = f2bf(v.z); pk.u[3] = f2bf(v.w);
      *(uint2*)&lt[row][c4] = pk.d;
    }
    __syncthreads();
    int j = threadIdx.x >> 2, seg = threadIdx.x & 3;  // j = n within tile
    int n = n0 + j;
    int h = n & 15, hd = (n & 1023) >> 4;
    int np = (n & ~1023) + h * 64 + hd;               // permuted row (head-grouped)
    union { u16 u[16]; uint4 q[2]; } o;
#pragma unroll
    for (int idx = 0; idx < 16; ++idx) o.u[idx] = lt[seg * 16 + idx][j];  // column read
    u16* dst = Wt + (size_t)np * DIM + k0 + seg * 16;
    *(uint4*)(dst) = o.q[0];
    *(uint4*)(dst + 8) = o.q[1];
  }
}

// ---------------- QKV GEMM v6: triple-buffer counted-vmcnt (R12, kept) ----------
#define GSTAGE(ADST, BDST, KT)                                                 \
  {                                                                            \
    const int koff = (KT) * 64; /* 32 k * 2 B */                               \
    _Pragma("unroll") for (int r = 0; r < 2; ++r) {                            \
      int l = r * 256 + t;        /* 16B chunk id 0..511 */                    \
      int row = l >> 2, pos = l & 3;                                           \
      int kc = pos ^ (row & 3);                                                \
      GLL16(Abase + row * 2048 + koff + kc * 16, (char*)(ADST) + l * 16);      \
      GLL16(Bbase + row * 2048 + koff + kc * 16, (char*)(BDST) + l * 16);      \
    }                                                                          \
  }

#define GCOMPUTE(AT, BT)                                                       \
  {                                                                            \
    bf16x8 af[4], bfr[4];                                                      \
    _Pragma("unroll") for (int mt = 0; mt < 4; ++mt) {                         \
      int row = wm + mt * 16 + c;                                              \
      int kc = quad ^ (row & 3);                                               \
      af[mt] = *(const bf16x8*)((const char*)(AT) + row * 64 + kc * 16);       \
    }                                                                          \
    _Pragma("unroll") for (int nt = 0; nt < 4; ++nt) {                         \
      int row = wn + nt * 16 + c;                                              \
      int kc = quad ^ (row & 3);                                               \
      bfr[nt] = *(const bf16x8*)((const char*)(BT) + row * 64 + kc * 16);      \
    }                                                                          \
    _Pragma("unroll") for (int mt = 0; mt < 4; ++mt)                           \
      _Pragma("unroll") for (int nt = 0; nt < 4; ++nt)                         \
        acc[mt][nt] = MFMA_BF16(af[mt], bfr[nt], acc[mt][nt]);                 \
  }

__global__ __launch_bounds__(256) void gemm_qkv_kernel(
    const u16* __restrict__ Ab, const u16* __restrict__ Bt, const float* __restrict__ bias,
    u16* __restrict__ Q, u16* __restrict__ K, u16* __restrict__ Vt) {
  __shared__ __align__(16) u16 A0[128 * 32];  // 8 KB x6 = 48 KB (3 blk/CU, = grid cap)
  __shared__ __align__(16) u16 A1[128 * 32];
  __shared__ __align__(16) u16 A2[128 * 32];
  __shared__ __align__(16) u16 B0[128 * 32];
  __shared__ __align__(16) u16 B1[128 * 32];
  __shared__ __align__(16) u16 B2[128 * 32];
  const int t = threadIdx.x;
  const int lane = t & 63, wave = t >> 6;
  const int c = lane & 15, quad = lane >> 4;
  // XCD swizzle: 96 consecutive block ids per XCD (768 = 8*96, bijective)
  const int wid = (blockIdx.x & 7) * 96 + (blockIdx.x >> 3);
  const int tm = wid / 24, tn = wid - tm * 24;
  const int wm = (wave >> 1) * 64, wn = (wave & 1) * 64;

  const char* Abase = (const char*)(Ab + (size_t)tm * 128 * DIM);
  const char* Bbase = (const char*)(Bt + (size_t)tn * 128 * DIM);

  f32x4 z = {0.f, 0.f, 0.f, 0.f};
  f32x4 acc[4][4];
#pragma unroll
  for (int i = 0; i < 4; ++i)
#pragma unroll
    for (int j = 0; j < 4; ++j) acc[i][j] = z;

  // prologue: stages 0,1 in flight; wait only stage 0 (4 loads of stage 1 remain)
  GSTAGE(A0, B0, 0);
  GSTAGE(A1, B1, 1);
  asm volatile("s_waitcnt vmcnt(4)" ::: "memory");
  __builtin_amdgcn_s_barrier();
  __builtin_amdgcn_sched_barrier(0);

  const u16 *pa = A0, *pb = B0;   // compute buffer (tile kt)
  const u16 *qa = A1, *qb = B1;   // next (tile kt+1)
  const u16 *ra = A2, *rb = B2;   // staging target (tile kt+2)
#pragma unroll 1
  for (int kt = 0; kt < 32; ++kt) {
    if (kt + 2 < 32) GSTAGE(ra, rb, kt + 2);  // 2 stages in flight
    GCOMPUTE(pa, pb);
    if (kt + 2 < 32) {
      asm volatile("s_waitcnt vmcnt(4)" ::: "memory");  // stage kt+1 landed
    } else {
      asm volatile("s_waitcnt vmcnt(0)" ::: "memory");  // tail drain
    }
    __builtin_amdgcn_s_barrier();   // raw: stage kt+2 stays in flight across it
    __builtin_amdgcn_sched_barrier(0);
    const u16* ta = pa; pa = qa; qa = ra; ra = ta;
    const u16* tb = pb; pb = qb; qb = rb; rb = tb;
  }

  // Epilogue (R8-proven): C/D layout col = lane&15, row = quad*4 + reg.
#pragma unroll
  for (int nt = 0; nt < 4; ++nt) {
    int np = tn * 128 + wn + nt * 16 + c;
    int which = np >> 10;
    int rem = np & 1023;
    int h = rem >> 6, hd = rem & 63;
    float bv = bias[(np & ~1023) + hd * 16 + h];  // bias in ORIGINAL column order
    float sc = (which == 0) ? CSC : 1.0f;
    float bvs = bv * sc;
#pragma unroll
    for (int mt = 0; mt < 4; ++mt) {
      int mbase = tm * 128 + wm + mt * 16 + quad * 4;
      int bI = mbase >> 11;
      int s0 = mbase & 2047;
      if (which == 2) {
        union { u16 u[4]; uint2 v; } p;
#pragma unroll
        for (int r = 0; r < 4; ++r) p.u[r] = f2bf(acc[mt][nt][r] + bv);
        *(uint2*)(Vt + ((size_t)(bI * NH + h) * HD + hd) * SEQ + s0) = p.v;  // [b,h,hd,s]
      } else {
        u16* dst = (which == 0) ? Q : K;
#pragma unroll
        for (int r = 0; r < 4; ++r)
          dst[((size_t)(bI * NH + h) * SEQ + (s0 + r)) * HD + hd] =
              f2bf(acc[mt][nt][r] * sc + bvs);
      }
    }
  }
}

// ---------------- Flash attention v17: qt-paired 8-wave blocks (R13, FINAL) -----
// R14 post-mortem: v18's counted-vmcnt port was neutral-to-negative (attn 50.4
// -> 51.3; total flat) -- by v17 the barrier drain is not first-order; the
// plateau is the serial QK->softmax->PV chain with no saturated pipe.
// Reverting to R13's v17 per the pre-committed decision rule: best measured
// total 155.3us. v17 = qt-paired 128 q-rows/block (8 waves; staging DMA +
// barriers per unit work halved vs v15; waves/CU unchanged), permlane
// P-transform (R4: conflicts 4.19M->0), ones-MFMA l-sum (R5), XCD bh grouping
// (R2: FETCH 69.7->12.3MB), setprio, all-__syncthreads discipline (R6: GLL
// staging is a block-level prefetch engine -- do not remove).
#define STAGE_KV(KDST, VDST, KTILE)                                            \
  {                                                                            \
    const char* Ktb = Kb + (size_t)(KTILE) * 8192;   /* 64 rows * 128 B */     \
    const char* Vtb = Vb + (size_t)(KTILE) * 128;    /* 64 cols * 2 B   */     \
    int l = t;                      /* 512 threads = 512 x 16B chunks */       \
    int row = l >> 3, pos = l & 7;                                             \
    int kc = pos ^ (row & 7);                                                  \
    GLL16(Ktb + row * 128 + kc * 16, (char*)(KDST) + l * 16);                  \
    GLL16(Vtb + row * 4096 + kc * 16, (char*)(VDST) + l * 16);                 \
  }

#define COMPUTE_TILE(KT, VT)                                                   \
  {                                                                            \
    f32x4 sT[2][2]; /* [mt2 = s_k 16-tile within wave's half][nt = s_q tile] */\
    sT[0][0] = z; sT[0][1] = z; sT[1][0] = z; sT[1][1] = z;                    \
    __builtin_amdgcn_s_setprio(1);                                             \
    _Pragma("unroll") for (int mt2 = 0; mt2 < 2; ++mt2) {                      \
      _Pragma("unroll") for (int ks = 0; ks < 2; ++ks) {                       \
        int row = ws * 32 + mt2 * 16 + c;                                      \
        int kc = (ks * 4 + quad) ^ (row & 7);                                  \
        bf16x8 kf = *(const bf16x8*)((const char*)(KT) + row * 128 + kc * 16); \
        sT[mt2][0] = MFMA_BF16(kf, qf[0][ks], sT[mt2][0]);                     \
        sT[mt2][1] = MFMA_BF16(kf, qf[1][ks], sT[mt2][1]);                     \
      }                                                                        \
    }                                                                          \
    __builtin_amdgcn_s_setprio(0);                                             \
    bf16x8 pf[2];                                                              \
    _Pragma("unroll") for (int nt = 0; nt < 2; ++nt) {                         \
      u32 pk[2][2];                                                            \
      _Pragma("unroll") for (int mt2 = 0; mt2 < 2; ++mt2) {                    \
        float p0 = fexp2(sT[mt2][nt][0]);                                      \
        float p1 = fexp2(sT[mt2][nt][1]);                                      \
        float p2 = fexp2(sT[mt2][nt][2]);                                      \
        float p3 = fexp2(sT[mt2][nt][3]);                                      \
        pk[mt2][0] = (u32)f2bf(p0) | ((u32)f2bf(p1) << 16);                    \
        pk[mt2][1] = (u32)f2bf(p2) | ((u32)f2bf(p3) << 16);                    \
      }                                                                        \
      uint4 wv = p_transform(pk[0][0], pk[0][1], pk[1][0], pk[1][1],           \
                             sl0, sl1, hi);                                    \
      pf[nt] = __builtin_bit_cast(bf16x8, wv);                                 \
    }                                                                          \
    __builtin_amdgcn_s_setprio(1);                                             \
    _Pragma("unroll") for (int mt = 0; mt < 4; ++mt) {                         \
      int row = mt * 16 + c;                                                   \
      int kc = vq ^ (row & 7);                                                 \
      bf16x8 vf = *(const bf16x8*)((const char*)(VT) + row * 128 + kc * 16);   \
      accO[mt][0] = MFMA_BF16(vf, pf[0], accO[mt][0]);                         \
      accO[mt][1] = MFMA_BF16(vf, pf[1], accO[mt][1]);                         \
    }                                                                          \
    acc_l[0] = MFMA_BF16(ones, pf[0], acc_l[0]);  /* col-sums of P = l partial */ \
    acc_l[1] = MFMA_BF16(ones, pf[1], acc_l[1]);                               \
    __builtin_amdgcn_s_setprio(0);                                             \
  }

__global__ __launch_bounds__(512, 4) void attn_kernel(
    const u16* __restrict__ Q, const u16* __restrict__ K,
    const u16* __restrict__ Vt, float* __restrict__ Out) {
  __shared__ __align__(16) u16 Ka[64 * 64];   // 8 KB  K buf A (Q tile0 staging / reduce wq2=0)
  __shared__ __align__(16) u16 Kb2[64 * 64];  // 8 KB  K buf B (reduce wq2=1)
  __shared__ __align__(16) u16 Va[64 * 64];   // 8 KB  V^T buf A (Q tile1 staging / reduce wq2=2)
  __shared__ __align__(16) u16 Vb2[64 * 64];  // 8 KB  V^T buf B (reduce wq2=3)
  __shared__ float lred[512];                 // 2 KB  l partials (4 wq2 x 128)
  const int t = threadIdx.x;
  const int lane = t & 63, wave = t >> 6;     // 8 waves
  const int c = lane & 15, quad = lane >> 4;
  const int wq2 = wave & 3, ws = wave >> 2;   // q 32-row group (of 128) / s_k half
  // XCD-aware swizzle: p%8 selects XCD; each XCD gets 4 whole bh's (2MB K/V in L2)
  const int p = blockIdx.x;                   // 512 blocks = 32 bh x 16 qt-pairs
  const int xcd = p & 7, slot = p >> 3;       // slot 0..63
  const int bh = xcd + ((slot >> 4) << 3);    // bh ≡ xcd (mod 8), 4 bh per XCD
  const int qtp = slot & 15;                  // q-tile-pair: rows qtp*128 .. +128
  const int h = bh & 15, b = bh >> 4;

  const u16* Qb = Q + ((size_t)bh * SEQ + qtp * 128) * HD;
  const char* Kb = (const char*)(K + (size_t)bh * SEQ * HD);
  const char* Vb = (const char*)(Vt + (size_t)bh * HD * SEQ);

  // stage Q pair: tile0 (rows 0-63) -> Ka, tile1 (rows 64-127) -> Va
  {
    int l = t;
    int row = l >> 3, pos = l & 7;
    int kc = pos ^ (row & 7);
    GLL16((const char*)Qb + row * 128 + kc * 16, (char*)Ka + l * 16);
    GLL16((const char*)Qb + 8192 + row * 128 + kc * 16, (char*)Va + l * 16);
  }
  __syncthreads();  // drain Q staging
  bf16x8 qf[2][2];  // [nt][ks]; wave's q rows = qtp*128 + wq2*32 + nt*16 + c
#pragma unroll
  for (int nt = 0; nt < 2; ++nt)
#pragma unroll
    for (int ks = 0; ks < 2; ++ks) {
      int row = (wq2 & 1) * 32 + nt * 16 + c;   // row within the 64-row tile
      int kc = (ks * 4 + quad) ^ (row & 7);
      const char* qbuf = (wq2 >> 1) ? (const char*)Va : (const char*)Ka;
      qf[nt][ks] = *(const bf16x8*)(qbuf + row * 128 + kc * 16);
    }
  __syncthreads();  // all waves done reading Ka/Va (Q); lgkm drained

  f32x4 z = {0.f, 0.f, 0.f, 0.f};
  f32x4 accO[4][2];  // [mt = hd tile][nt]; partial over wave's s_k half
#pragma unroll
  for (int i = 0; i < 4; ++i) { accO[i][0] = z; accO[i][1] = z; }
  f32x4 acc_l[2] = {z, z};  // l partials via ones-MFMA (rows identical)
  const uint4 onesw = {0x3F803F80u, 0x3F803F80u, 0x3F803F80u, 0x3F803F80u};
  const bf16x8 ones = __builtin_bit_cast(bf16x8, onesw);

  const int sl0 = c + 16 * ((quad & 1) * 2);  // shuffle source lanes (fallback path)
  const int sl1 = sl0 + 16;
  const bool hi = quad >= 2;
  const int vq = ws * 4 + quad;  // V^T chunk index: s_k = ws*32 + quad*8 + j

  STAGE_KV(Ka, Va, 0);
  __syncthreads();  // drain tile 0

  for (int kt = 0; kt < 32; kt += 2) {
    STAGE_KV(Kb2, Vb2, kt + 1);       // in flight across compute of tile kt
    COMPUTE_TILE(Ka, Va);
    __syncthreads();                  // drains tile kt+1; frees Ka/Va
    if (kt + 2 < 32) STAGE_KV(Ka, Va, kt + 2);
    COMPUTE_TILE(Kb2, Vb2);
    __syncthreads();                  // drains tile kt+2; frees Kb2/Vb2
  }

  // ---- cross-wave reduce over ws pairs (LDS buffers are free now) ----
  // acc_l rows identical (ones-MFMA): [0] = this wave's 32-k partial l for
  // q-col c, replicated across quads. Pair (ws=0,wq2) <-> (ws=1,wq2).
  float sm[2];
  sm[0] = acc_l[0][0];
  sm[1] = acc_l[1][0];
  float* fb = (float*)((wq2 & 2) ? ((wq2 & 1) ? (void*)Vb2 : (void*)Va)
                                 : ((wq2 & 1) ? (void*)Kb2 : (void*)Ka));
  if (ws == 1) {
#pragma unroll
    for (int mt = 0; mt < 4; ++mt)
#pragma unroll
      for (int nt = 0; nt < 2; ++nt)
        *(f32x4*)(fb + (mt * 2 + nt) * 256 + lane * 4) = accO[mt][nt];
    lred[wq2 * 128 + lane * 2] = sm[0];
    lred[wq2 * 128 + lane * 2 + 1] = sm[1];
  }
  __syncthreads();
  if (ws == 0) {
#pragma unroll
    for (int mt = 0; mt < 4; ++mt)
#pragma unroll
      for (int nt = 0; nt < 2; ++nt)
        accO[mt][nt] += *(const f32x4*)(fb + (mt * 2 + nt) * 256 + lane * 4);
    float inv0 = 1.f / (sm[0] + lred[wq2 * 128 + lane * 2]);
    float inv1 = 1.f / (sm[1] + lred[wq2 * 128 + lane * 2 + 1]);
    int s0 = qtp * 128 + wq2 * 32 + c;
#pragma unroll
    for (int mt = 0; mt < 4; ++mt) {
#pragma unroll
      for (int nt = 0; nt < 2; ++nt) {
        float inv = nt ? inv1 : inv0;
        float4 o;
        o.x = accO[mt][nt][0] * inv;
        o.y = accO[mt][nt][1] * inv;
        o.z = accO[mt][nt][2] * inv;
        o.w = accO[mt][nt][3] * inv;
        size_t off = ((size_t)(b * SEQ + s0 + nt * 16)) * DIM + h * HD + mt * 16 + quad * 4;
        *(float4*)(Out + off) = o;
      }
    }
  }
}

extern "C" void kernel_launch(void* const* d_in, const int* in_sizes, int n_in,
                              void* d_out, int out_size, void* d_ws, size_t ws_size,
                              hipStream_t stream) {
  (void)in_sizes; (void)n_in; (void)out_size; (void)ws_size;
  const float* emb = (const float*)d_in[0];
  const float* W = (const float*)d_in[1];
  const float* bias = (const float*)d_in[2];
  float* out = (float*)d_out;
  char* ws = (char*)d_ws;
  // ws layout (bytes): Abf 8 MB | Wt 6 MB | Q 8 MB | K 8 MB | Vt 8 MB  (total ~38 MB)
  u16* Ab = (u16*)ws;
  u16* Wt = (u16*)(ws + 8388608);
  u16* Qd = (u16*)(ws + 14680064);
  u16* Kd = (u16*)(ws + 23068672);
  u16* Vd = (u16*)(ws + 31457280);

  conv_kernel<<<4864, 256, 0, stream>>>(emb, Ab, W, Wt);   // 4096 A-blocks + 768 W-tiles
  gemm_qkv_kernel<<<768, 256, 0, stream>>>(Ab, Wt, bias, Qd, Kd, Vd);
  attn_kernel<<<512, 512, 0, stream>>>(Qd, Kd, Vd, out);   // (b,h) x 16 q-tile-pairs of 128
}